// Round 13
// baseline (49.607 us; speedup 1.0000x reference)
//
#include <hip/hip_runtime.h>
#include <math.h>

// Mamba selective scan:
//   u, delta, z : (2, 2048, 1024) f32 ; A : (2048, 16) f32
//   B, C : (2, 16, 1024) f32 ; D, delta_bias : (2048,) f32 ; softplus flag
// Output y : (2, 2048, 1024) f32
//
// v18 = v16 (49.4 us: RPB=4, B/C LDS tiles, proven combine) + LDS-pipe cuts:
//   - tile layout [il][j][cg] float2, stride 65: ALL tile accesses are
//     ds_read_b64 / ds_write_b64 at 2-way bank aliasing (free) -- the b128
//     4-way conflict (3.4M cycles) is inherent (b128 => 8 slots/32 lanes),
//     b64 has 16 slots => 2-way. Transform emits k-major to keep staging
//     global reads coalesced.
//   - y_core in 8 regs (static idx via full unroll + cndmask on h);
//     epilogue stores 32B/lane dense from regs. Removes 32 LDS ops and the
//     final barrier. +8 VGPR only (v17 lesson: keep persistent arrays <=16).
//   - everything else byte-identical to v16 (barrier scheme, combine, du_s).
//   - NO register cap (r2/r4). Tripwires: WRITE_SIZE == 16384 KB,
//     SQ_LDS_BANK_CONFLICT < 1M.
constexpr int Bsz = 2, Dm = 2048, L = 1024, N = 16;
constexpr int CL = 16;          // chunk length (steps per lane)
constexpr int WPR = 2;          // waves per row
constexpr int RPB = 4;          // rows per block
constexpr int TPB = RPB * WPR * 64;  // 512
constexpr int TI = 2;           // steps per LDS tile
constexpr int NT = CL / TI;     // 8 tiles per pass
constexpr int ISTR2 = 65;       // du_s float2 stride per step (64 + 1 pad)
constexpr int LROW2 = CL * ISTR2;    // 1040 float2 per row
constexpr int TS2 = 8 * 65;     // tile: float2 stride per il (8 j-slots x 65)
constexpr float LOG2E = 1.4426950408889634f;
constexpr float RLOG2E = 0.6931471805599453f;   // ln 2

#define EXP2(x) __builtin_amdgcn_exp2f(x)

// ---------------------------------------------------------------------------
// Transform B,C into scan layout (chunk length 16), k-MAJOR:
//   Bs[b*4096 + i*256 + k*64 + cg] = float4 { B[b][4k+q][cg*16+i] } q=0..3
// Staging thread tid of tile t then reads Bs[t*512 + tid] fully coalesced.
// ---------------------------------------------------------------------------
__global__ __launch_bounds__(256) void transform_bc_kernel(
    const float* __restrict__ B_g, const float* __restrict__ C_g,
    float4* __restrict__ Bs, float4* __restrict__ Cs)
{
    const int o = threadIdx.x + 256 * blockIdx.x;   // 4096 float4 per (b, src)
    const int b = blockIdx.y;
    const float* __restrict__ src = blockIdx.z ? C_g : B_g;
    float4* __restrict__ dst = blockIdx.z ? Cs : Bs;
    const int cg = o & 63, k = (o >> 6) & 3, i = o >> 8;
    const int l = cg * CL + i;
    float4 v;
    v.x = src[(size_t)(b * N + 4 * k + 0) * L + l];
    v.y = src[(size_t)(b * N + 4 * k + 1) * L + l];
    v.z = src[(size_t)(b * N + 4 * k + 2) * L + l];
    v.w = src[(size_t)(b * N + 4 * k + 3) * L + l];
    dst[(size_t)b * 4096 + o] = v;
}

// ---------------------------------------------------------------------------
// Scan kernel. 8 waves/block = 4 rows x 2 waves. Wave handles 32 chunks of
// 16 steps. lane = h*32 + c: h = n-half, c = chunk-in-wave. cg = W*32+c.
// B/C tiles shared by all 4 rows via LDS (b64 conflict-free layout).
// ---------------------------------------------------------------------------
template<bool XF>
__global__ __launch_bounds__(TPB) void mamba_scan18_kernel(
    const float* __restrict__ u_g, const float* __restrict__ delta_g,
    const float* __restrict__ A_g,
    const float* __restrict__ B_g, const float* __restrict__ C_g,
    const float4* __restrict__ Bs, const float4* __restrict__ Cs,
    const float* __restrict__ D_g, const float* __restrict__ z_g,
    const float* __restrict__ bias_g, const int* __restrict__ sp_g,
    float* __restrict__ y_g)
{
    __shared__ float2 du_s[RPB * LROW2];  // [r][i*65+cg] = (dtp,u)
    __shared__ float2 tb2[2][TI * TS2];   // 16.6 KB: tile buffers (b64 layout)
    __shared__ float xw_s[RPB][16];       // per-row wave0 totals

    const int tid = threadIdx.x;
    const int wid = tid >> 6;                  // wave id 0..7
    const int lane = tid & 63;
    const int W = wid & 1;                     // wave-in-row
    const int r = wid >> 1;                    // local row 0..3
    const int h = lane >> 5;                   // n-half
    const int c = lane & 31;                   // chunk-in-wave
    const int cg = W * 32 + c;                 // global chunk 0..63
    const int row = blockIdx.x * RPB + r;
    const int b = row >> 11;                   // row / Dm (blocks never straddle)
    const int d = row & (Dm - 1);
    const size_t Bb = (size_t)b * 4096;        // workspace base (float4 units)
    const int lb = r * LROW2;
    const int t128 = tid & 127;                // thread-in-row (2 waves)
    // staging: wave wid owns (il = wid>>2, k = wid&3) for all 64 cg
    const int stg0 = (wid >> 2) * TS2 + (2 * (wid & 3)) * 65 + lane;
    const int stg1 = stg0 + 65;
    // tile read base for this lane: j = 4h at column cg
    const int trb = (4 * h) * 65 + cg;

    float4 sB, sC;
    if (XF) sB = Bs[Bb + tid];                 // tile 0 of B, issued early

    // ---- Phase 0: coalesced load of delta/u -> step-major packed LDS ----
#pragma unroll
    for (int p = 0; p < 2; ++p) {
        const int l0 = 4 * t128 + 512 * p;
        const size_t gb = (size_t)row * L + l0;
        const float4 d4 = *reinterpret_cast<const float4*>(&delta_g[gb]);
        const float4 u4 = *reinterpret_cast<const float4*>(&u_g[gb]);
        const float bias = bias_g[d];
        const int sp = sp_g[0];
#pragma unroll
        for (int k = 0; k < 4; ++k) {
            const int li = l0 + k;
            const float t = (&d4.x)[k] + bias;
            // softplus: max(t,0) + ln(1 + 2^(-|t|*log2e))
            const float e = EXP2(-fabsf(t) * LOG2E);
            const float p_ = sp ? (fmaxf(t, 0.f) +
                                   __builtin_amdgcn_logf(1.f + e) * RLOG2E)
                                : t;
            const int a = (li & (CL - 1)) * ISTR2 + (li >> 4);  // [step][chunk]
            du_s[lb + a] = make_float2(p_, (&u4.x)[k]);
        }
    }
    float A2[8];
#pragma unroll
    for (int g = 0; g < 2; ++g) {
        const float4 a4 = *reinterpret_cast<const float4*>(&A_g[d * N + h * 8 + g * 4]);
        A2[g * 4 + 0] = a4.x * LOG2E; A2[g * 4 + 1] = a4.y * LOG2E;
        A2[g * 4 + 2] = a4.z * LOG2E; A2[g * 4 + 3] = a4.w * LOG2E;
    }
    if (XF) {                                  // stage tile 0 (B) for pass 1
        tb2[0][stg0] = make_float2(sB.x, sB.y);
        tb2[0][stg1] = make_float2(sB.z, sB.w);
    }
    __syncthreads();

    // ---- Pass 1: chunk-local zero-init scan; B via b64 LDS tiles (dbuf) ----
    float x[8], y[8];
#pragma unroll
    for (int n = 0; n < 8; ++n) { x[n] = 0.f; y[n] = 0.f; }
    float ssum = 0.f;

    if (XF) {
#pragma unroll
        for (int t = 0; t < NT; ++t) {
            if (t + 1 < NT) sB = Bs[Bb + (t + 1) * 512 + tid];  // prefetch
#pragma unroll
            for (int il = 0; il < TI; ++il) {
                const int i = t * TI + il;
                const float2 du = du_s[lb + i * ISTR2 + cg];
                const float dtp = du.x;
                const float dtu = du.x * du.y;
                ssum += dtp;
                const int rb = il * TS2 + trb;
                const float2 q0 = tb2[t & 1][rb];
                const float2 q1 = tb2[t & 1][rb + 65];
                const float2 q2 = tb2[t & 1][rb + 130];
                const float2 q3 = tb2[t & 1][rb + 195];
                const float bv[8] = {q0.x, q0.y, q1.x, q1.y,
                                     q2.x, q2.y, q3.x, q3.y};
#pragma unroll
                for (int n = 0; n < 8; ++n) {
                    const float a = EXP2(dtp * A2[n]);
                    x[n] = fmaf(a, x[n], dtu * bv[n]);
                }
            }
            if (t + 1 < NT) {
                tb2[(t + 1) & 1][stg0] = make_float2(sB.x, sB.y);
                tb2[(t + 1) & 1][stg1] = make_float2(sB.z, sB.w);
            }
            __syncthreads();                   // end tile epoch
        }
    } else {
#pragma unroll
        for (int i = 0; i < CL; ++i) {
            const float2 du = du_s[lb + i * ISTR2 + cg];
            const float dtp = du.x;
            const float dtu = du.x * du.y;
            ssum += dtp;
            const int l = cg * CL + i;
            const int k0 = 2 * h;
            float4 B0, B1;
#pragma unroll
            for (int q = 0; q < 4; ++q) {
                (&B0.x)[q] = B_g[(size_t)(b * N + 4 * k0 + q) * L + l];
                (&B1.x)[q] = B_g[(size_t)(b * N + 4 * k0 + 4 + q) * L + l];
            }
            const float bv[8] = {B0.x, B0.y, B0.z, B0.w, B1.x, B1.y, B1.z, B1.w};
#pragma unroll
            for (int n = 0; n < 8; ++n) {
                const float a = EXP2(dtp * A2[n]);
                x[n] = fmaf(a, x[n], dtu * bv[n]);
            }
        }
    }

    // issue pass-2 tile 0 loads early (latency hides under combine)
    if (XF) { sB = Bs[Bb + tid]; sC = Cs[Bb + tid]; }

    // ---- Combine level 1: 32-lane segmented inclusive scan of (P, x) ----
    float P[8];
#pragma unroll
    for (int n = 0; n < 8; ++n) P[n] = EXP2(A2[n] * ssum);
#pragma unroll
    for (int s = 1; s < 32; s <<= 1) {
        const bool ok = (c >= s);
#pragma unroll
        for (int n = 0; n < 8; ++n) {
            const float xp = __shfl_up(x[n], s, 32);
            const float Pp = __shfl_up(P[n], s, 32);
            if (ok) {
                x[n] = fmaf(P[n], xp, x[n]);
                P[n] = P[n] * Pp;
            }
        }
    }

    // ---- Combine level 2 publish + stage pass-2 tile 0; ONE barrier ----
    if (W == 0 && c == 31) {
#pragma unroll
        for (int n = 0; n < 8; ++n) xw_s[r][h * 8 + n] = x[n];
    }
    if (XF) {
        tb2[0][stg0] = make_float2(sB.x, sB.y);
        tb2[0][stg1] = make_float2(sB.z, sB.w);
        tb2[1][stg0] = make_float2(sC.x, sC.y);
        tb2[1][stg1] = make_float2(sC.z, sC.w);
    }
    __syncthreads();

    // exclusive shift within segment + wave1 prepends wave0's total
    float xt[8];
#pragma unroll
    for (int n = 0; n < 8; ++n) xt[n] = xw_s[r][h * 8 + n];
#pragma unroll
    for (int n = 0; n < 8; ++n) {
        const float xi = __shfl_up(x[n], 1, 32);
        const float Pi = __shfl_up(P[n], 1, 32);
        const float xe = (c == 0) ? 0.f : xi;
        const float Pe = (c == 0) ? 1.f : Pi;
        x[n] = W ? fmaf(Pe, xt[n], xe) : xe;
    }

    // ---- Pass 2: rescan with init states; y -> registers ----
    const float Dd = D_g[d];
    if (XF) {
#pragma unroll
        for (int t = 0; t < NT; ++t) {
            if (t + 1 < NT) {
                sB = Bs[Bb + (t + 1) * 512 + tid];   // prefetch next tile
                sC = Cs[Bb + (t + 1) * 512 + tid];
            }
#pragma unroll
            for (int il = 0; il < TI; ++il) {
                const int i = t * TI + il;
                const float2 du = du_s[lb + i * ISTR2 + cg];
                const float dtp = du.x;
                const float uu = du.y;
                const float dtu = dtp * uu;
                const int rb = il * TS2 + trb;
                const float2 b0 = tb2[0][rb];
                const float2 b1 = tb2[0][rb + 65];
                const float2 b2 = tb2[0][rb + 130];
                const float2 b3 = tb2[0][rb + 195];
                const float2 c0 = tb2[1][rb];
                const float2 c1 = tb2[1][rb + 65];
                const float2 c2 = tb2[1][rb + 130];
                const float2 c3 = tb2[1][rb + 195];
                const float bv[8] = {b0.x, b0.y, b1.x, b1.y,
                                     b2.x, b2.y, b3.x, b3.y};
                const float cv[8] = {c0.x, c0.y, c1.x, c1.y,
                                     c2.x, c2.y, c3.x, c3.y};
                float acc = 0.f;
#pragma unroll
                for (int n = 0; n < 8; ++n) {
                    const float a = EXP2(dtp * A2[n]);
                    x[n] = fmaf(a, x[n], dtu * bv[n]);
                    acc = fmaf(x[n], cv[n], acc);
                }
                acc += __shfl_xor(acc, 32, 64);    // both halves get full sum
                const float yv = fmaf(uu, Dd, acc);
                y[i & 7] = ((i >> 3) == h) ? yv : y[i & 7];   // static idx
            }
            __syncthreads();                       // all waves done with tile t
            if (t + 1 < NT) {
                tb2[0][stg0] = make_float2(sB.x, sB.y);
                tb2[0][stg1] = make_float2(sB.z, sB.w);
                tb2[1][stg0] = make_float2(sC.x, sC.y);
                tb2[1][stg1] = make_float2(sC.z, sC.w);
                __syncthreads();                   // tile t+1 visible
            }
        }
    } else {
#pragma unroll
        for (int i = 0; i < CL; ++i) {
            const float2 du = du_s[lb + i * ISTR2 + cg];
            const float dtp = du.x;
            const float uu = du.y;
            const float dtu = dtp * uu;
            const int l = cg * CL + i;
            const int k0 = 2 * h;
            float4 B0, B1, C0, C1;
#pragma unroll
            for (int q = 0; q < 4; ++q) {
                (&B0.x)[q] = B_g[(size_t)(b * N + 4 * k0 + q) * L + l];
                (&B1.x)[q] = B_g[(size_t)(b * N + 4 * k0 + 4 + q) * L + l];
                (&C0.x)[q] = C_g[(size_t)(b * N + 4 * k0 + q) * L + l];
                (&C1.x)[q] = C_g[(size_t)(b * N + 4 * k0 + 4 + q) * L + l];
            }
            const float bv[8] = {B0.x, B0.y, B0.z, B0.w, B1.x, B1.y, B1.z, B1.w};
            const float cv[8] = {C0.x, C0.y, C0.z, C0.w, C1.x, C1.y, C1.z, C1.w};
            float acc = 0.f;
#pragma unroll
            for (int n = 0; n < 8; ++n) {
                const float a = EXP2(dtp * A2[n]);
                x[n] = fmaf(a, x[n], dtu * bv[n]);
                acc = fmaf(x[n], cv[n], acc);
            }
            acc += __shfl_xor(acc, 32, 64);
            const float yv = fmaf(uu, Dd, acc);
            y[i & 7] = ((i >> 3) == h) ? yv : y[i & 7];
        }
    }

    // ---- Epilogue: per-lane z read (32B), silu gate, y store from regs ----
    // lane (h,c) owns elements [cg*16 + h*8, +8); wave coverage dense.
    {
        const size_t gz = (size_t)row * L + cg * CL + h * 8;
        const float4 z0 = *reinterpret_cast<const float4*>(&z_g[gz]);
        const float4 z1 = *reinterpret_cast<const float4*>(&z_g[gz + 4]);
        float out[8];
#pragma unroll
        for (int j = 0; j < 8; ++j) {
            const float zv = (j < 4) ? (&z0.x)[j] : (&z1.x)[j - 4];
            const float e = EXP2(-zv * LOG2E);
            const float sig = __builtin_amdgcn_rcpf(1.f + e);
            out[j] = y[j] * (zv * sig);
        }
        *reinterpret_cast<float4*>(&y_g[gz]) =
            make_float4(out[0], out[1], out[2], out[3]);
        *reinterpret_cast<float4*>(&y_g[gz + 4]) =
            make_float4(out[4], out[5], out[6], out[7]);
    }
}

extern "C" void kernel_launch(void* const* d_in, const int* in_sizes, int n_in,
                              void* d_out, int out_size, void* d_ws, size_t ws_size,
                              hipStream_t stream) {
    const float* u     = (const float*)d_in[0];
    const float* delta = (const float*)d_in[1];
    const float* A     = (const float*)d_in[2];
    const float* B     = (const float*)d_in[3];
    const float* C     = (const float*)d_in[4];
    const float* D     = (const float*)d_in[5];
    const float* z     = (const float*)d_in[6];
    const float* bias  = (const float*)d_in[7];
    const int*   sp    = (const int*)d_in[8];
    float* y = (float*)d_out;

    const size_t bc_bytes = (size_t)Bsz * 4096 * sizeof(float4);  // 128 KB each
    const bool xf = ws_size >= 2 * bc_bytes;
    float4* Bs = (float4*)d_ws;
    float4* Cs = (float4*)((char*)d_ws + bc_bytes);

    if (xf) {
        transform_bc_kernel<<<dim3(16, Bsz, 2), 256, 0, stream>>>(B, C, Bs, Cs);
        mamba_scan18_kernel<true><<<dim3((Bsz * Dm) / RPB), TPB, 0, stream>>>(
            u, delta, A, B, C, Bs, Cs, D, z, bias, sp, y);
    } else {
        mamba_scan18_kernel<false><<<dim3((Bsz * Dm) / RPB), TPB, 0, stream>>>(
            u, delta, A, B, C, Bs, Cs, D, z, bias, sp, y);
    }
}

// Round 14
// 49.366 us; speedup vs baseline: 1.0049x; 1.0049x over previous
//
#include <hip/hip_runtime.h>
#include <math.h>

// Mamba selective scan:
//   u, delta, z : (2, 2048, 1024) f32 ; A : (2048, 16) f32
//   B, C : (2, 16, 1024) f32 ; D, delta_bias : (2048,) f32 ; softplus flag
// Output y : (2, 2048, 1024) f32
//
// v19 = v18 (49.4 us: b64 conflict-free tiles, y-in-regs, proven combine)
//       + NON-DRAINING barrier pipeline (r13 post-mortem: conflicts->0 gave
//       +0; residual stall = per-epoch vmcnt(0) drain at __syncthreads):
//   - raw s_barrier with lgkmcnt(0)-only wait (HK/m201 pattern): LDS
//     visibility kept, global register prefetches SURVIVE barriers.
//   - depth-2 epoch prefetch: tile t+3 issued at epoch t, LDS-written at
//     epoch t+2 -> >=2 epochs to land; no exposed L2 latency anywhere.
//   - pass 2 retiled to 1-step {B_i,C_i} tiles (same 16.6KB), ping-pong
//     double-buffer, ONE barrier per step (no restage double-barrier).
//   - LDS 50KB (3 blocks/CU), NO reg caps. Tripwires: WRITE_SIZE==16384KB,
//     VGPR<=84, conflicts ~0.
constexpr int Bsz = 2, Dm = 2048, L = 1024, N = 16;
constexpr int CL = 16;          // chunk length (steps per lane)
constexpr int WPR = 2;          // waves per row
constexpr int RPB = 4;          // rows per block
constexpr int TPB = RPB * WPR * 64;  // 512
constexpr int NT = 8;           // pass-1 tiles (2 steps each)
constexpr int ISTR2 = 65;       // du_s float2 stride per step (64 + 1 pad)
constexpr int LROW2 = CL * ISTR2;    // 1040 float2 per row
constexpr int TS2 = 8 * 65;     // 520 float2: one step-group (8 j-rows x 65)
constexpr float LOG2E = 1.4426950408889634f;
constexpr float RLOG2E = 0.6931471805599453f;   // ln 2

#define EXP2(x) __builtin_amdgcn_exp2f(x)

// Workgroup barrier WITHOUT the vmcnt(0) drain __syncthreads inserts.
// lgkmcnt(0) makes this wave's LDS writes visible before the barrier;
// in-flight global->register loads keep counting across it.
__device__ __forceinline__ void wg_barrier() {
    asm volatile("s_waitcnt lgkmcnt(0)" ::: "memory");
    __builtin_amdgcn_s_barrier();
    asm volatile("" ::: "memory");
}

// ---------------------------------------------------------------------------
// Transform B,C into scan layout (chunk length 16), k-MAJOR:
//   Bs[b*4096 + i*256 + k*64 + cg] = float4 { B[b][4k+q][cg*16+i] } q=0..3
// Staging reads are then fully coalesced per tile.
// ---------------------------------------------------------------------------
__global__ __launch_bounds__(256) void transform_bc_kernel(
    const float* __restrict__ B_g, const float* __restrict__ C_g,
    float4* __restrict__ Bs, float4* __restrict__ Cs)
{
    const int o = threadIdx.x + 256 * blockIdx.x;   // 4096 float4 per (b, src)
    const int b = blockIdx.y;
    const float* __restrict__ src = blockIdx.z ? C_g : B_g;
    float4* __restrict__ dst = blockIdx.z ? Cs : Bs;
    const int cg = o & 63, k = (o >> 6) & 3, i = o >> 8;
    const int l = cg * CL + i;
    float4 v;
    v.x = src[(size_t)(b * N + 4 * k + 0) * L + l];
    v.y = src[(size_t)(b * N + 4 * k + 1) * L + l];
    v.z = src[(size_t)(b * N + 4 * k + 2) * L + l];
    v.w = src[(size_t)(b * N + 4 * k + 3) * L + l];
    dst[(size_t)b * 4096 + o] = v;
}

// ---------------------------------------------------------------------------
// Scan kernel. 8 waves/block = 4 rows x 2 waves. Wave handles 32 chunks of
// 16 steps. lane = h*32 + c: h = n-half, c = chunk-in-wave. cg = W*32+c.
// B/C tiles shared by all 4 rows via LDS (b64 conflict-free layout).
// ---------------------------------------------------------------------------
template<bool XF>
__global__ __launch_bounds__(TPB) void mamba_scan19_kernel(
    const float* __restrict__ u_g, const float* __restrict__ delta_g,
    const float* __restrict__ A_g,
    const float* __restrict__ B_g, const float* __restrict__ C_g,
    const float4* __restrict__ Bs, const float4* __restrict__ Cs,
    const float* __restrict__ D_g, const float* __restrict__ z_g,
    const float* __restrict__ bias_g, const int* __restrict__ sp_g,
    float* __restrict__ y_g)
{
    __shared__ float2 du_s[RPB * LROW2];  // [r][i*65+cg] = (dtp,u)
    __shared__ float2 tb2[2][2 * TS2];    // 16.6 KB tile ping-pong buffers
                                          // pass1: [buf][il*520 + j*65+cg]
                                          // pass2: [buf][bc*520 + j*65+cg]
    __shared__ float xw_s[RPB][16];       // per-row wave0 totals

    const int tid = threadIdx.x;
    const int wid = tid >> 6;                  // wave id 0..7
    const int lane = tid & 63;
    const int W = wid & 1;                     // wave-in-row
    const int r = wid >> 1;                    // local row 0..3
    const int h = lane >> 5;                   // n-half
    const int c = lane & 31;                   // chunk-in-wave
    const int cg = W * 32 + c;                 // global chunk 0..63
    const int row = blockIdx.x * RPB + r;
    const int b = row >> 11;                   // row / Dm (blocks never straddle)
    const int d = row & (Dm - 1);
    const size_t Bb = (size_t)b * 4096;        // workspace base (float4 units)
    const int lb = r * LROW2;
    const int t128 = tid & 127;                // thread-in-row (2 waves)
    // pass-1 staging: wave wid owns (il = wid>>2, k = wid&3) for all 64 cg
    const int stg0 = (wid >> 2) * TS2 + (2 * (wid & 3)) * 65 + lane;
    const int stg1 = stg0 + 65;
    // pass-2 staging: threads 0-255 stage B, 256-511 stage C (1 step each)
    const int bc = tid >> 8;
    const int t256 = tid & 255;
    const int pstg0 = bc * TS2 + (2 * ((t256 >> 6) & 3)) * 65 + (t256 & 63);
    const int pstg1 = pstg0 + 65;
    const float4* __restrict__ psrc = (bc ? Cs : Bs) + Bb;
    // tile read base for this lane: j = 4h at column cg
    const int trb = (4 * h) * 65 + cg;

    float4 s0, s1;
    if (XF) s0 = Bs[Bb + tid];                 // pass-1 tile 0, issued early

    // ---- Phase 0: coalesced load of delta/u -> step-major packed LDS ----
    {
        const float bias = bias_g[d];
        const int sp = sp_g[0];
#pragma unroll
        for (int p = 0; p < 2; ++p) {
            const int l0 = 4 * t128 + 512 * p;
            const size_t gb = (size_t)row * L + l0;
            const float4 d4 = *reinterpret_cast<const float4*>(&delta_g[gb]);
            const float4 u4 = *reinterpret_cast<const float4*>(&u_g[gb]);
#pragma unroll
            for (int k = 0; k < 4; ++k) {
                const int li = l0 + k;
                const float t = (&d4.x)[k] + bias;
                // softplus: max(t,0) + ln(1 + 2^(-|t|*log2e))
                const float e = EXP2(-fabsf(t) * LOG2E);
                const float p_ = sp ? (fmaxf(t, 0.f) +
                                       __builtin_amdgcn_logf(1.f + e) * RLOG2E)
                                    : t;
                const int a = (li & (CL - 1)) * ISTR2 + (li >> 4);
                du_s[lb + a] = make_float2(p_, (&u4.x)[k]);
            }
        }
    }
    float A2[8];
#pragma unroll
    for (int g = 0; g < 2; ++g) {
        const float4 a4 = *reinterpret_cast<const float4*>(&A_g[d * N + h * 8 + g * 4]);
        A2[g * 4 + 0] = a4.x * LOG2E; A2[g * 4 + 1] = a4.y * LOG2E;
        A2[g * 4 + 2] = a4.z * LOG2E; A2[g * 4 + 3] = a4.w * LOG2E;
    }
    if (XF) {
        tb2[0][stg0] = make_float2(s0.x, s0.y);     // stage tile 0
        tb2[0][stg1] = make_float2(s0.z, s0.w);
        s0 = Bs[Bb + 512 + tid];                    // tile 1 (in flight)
        s1 = Bs[Bb + 1024 + tid];                   // tile 2 (in flight)
    }
    wg_barrier();

    // ---- Pass 1: zero-init scan; 8 epochs, depth-2 prefetch pipeline ----
    float x[8], y[8];
#pragma unroll
    for (int n = 0; n < 8; ++n) { x[n] = 0.f; y[n] = 0.f; }
    float ssum = 0.f;

    if (XF) {
#pragma unroll
        for (int t = 0; t < NT; ++t) {
#pragma unroll
            for (int il = 0; il < 2; ++il) {
                const int i = 2 * t + il;
                const float2 du = du_s[lb + i * ISTR2 + cg];
                const float dtp = du.x;
                const float dtu = du.x * du.y;
                ssum += dtp;
                const int rb = il * TS2 + trb;
                const float2 q0 = tb2[t & 1][rb];
                const float2 q1 = tb2[t & 1][rb + 65];
                const float2 q2 = tb2[t & 1][rb + 130];
                const float2 q3 = tb2[t & 1][rb + 195];
                const float bv[8] = {q0.x, q0.y, q1.x, q1.y,
                                     q2.x, q2.y, q3.x, q3.y};
#pragma unroll
                for (int n = 0; n < 8; ++n) {
                    const float a = EXP2(dtp * A2[n]);
                    x[n] = fmaf(a, x[n], dtu * bv[n]);
                }
            }
            if (t + 1 < NT) {                       // write tile t+1 (loaded >=1 epoch ago)
                const float4 sv = (t & 1) ? s1 : s0;
                tb2[(t + 1) & 1][stg0] = make_float2(sv.x, sv.y);
                tb2[(t + 1) & 1][stg1] = make_float2(sv.z, sv.w);
            }
            if (t + 3 < NT) {                       // issue tile t+3 (2 epochs ahead)
                if (t & 1) s1 = Bs[Bb + (t + 3) * 512 + tid];
                else       s0 = Bs[Bb + (t + 3) * 512 + tid];
            }
            if (t + 1 < NT) wg_barrier();
        }
    } else {
#pragma unroll
        for (int i = 0; i < CL; ++i) {
            const float2 du = du_s[lb + i * ISTR2 + cg];
            const float dtp = du.x;
            const float dtu = du.x * du.y;
            ssum += dtp;
            const int l = cg * CL + i;
            const int k0 = 2 * h;
            float4 B0, B1;
#pragma unroll
            for (int q = 0; q < 4; ++q) {
                (&B0.x)[q] = B_g[(size_t)(b * N + 4 * k0 + q) * L + l];
                (&B1.x)[q] = B_g[(size_t)(b * N + 4 * k0 + 4 + q) * L + l];
            }
            const float bv[8] = {B0.x, B0.y, B0.z, B0.w, B1.x, B1.y, B1.z, B1.w};
#pragma unroll
            for (int n = 0; n < 8; ++n) {
                const float a = EXP2(dtp * A2[n]);
                x[n] = fmaf(a, x[n], dtu * bv[n]);
            }
        }
    }

    // issue pass-2 step 0 load (latency hides under the combine)
    float4 p0, p1;
    if (XF) p0 = psrc[t256];

    // ---- Combine level 1: 32-lane segmented inclusive scan of (P, x) ----
    float P[8];
#pragma unroll
    for (int n = 0; n < 8; ++n) P[n] = EXP2(A2[n] * ssum);
#pragma unroll
    for (int s = 1; s < 32; s <<= 1) {
        const bool ok = (c >= s);
#pragma unroll
        for (int n = 0; n < 8; ++n) {
            const float xp = __shfl_up(x[n], s, 32);
            const float Pp = __shfl_up(P[n], s, 32);
            if (ok) {
                x[n] = fmaf(P[n], xp, x[n]);
                P[n] = P[n] * Pp;
            }
        }
    }

    // ---- Combine level 2 publish + stage pass-2 step 0; ONE barrier ----
    if (W == 0 && c == 31) {
#pragma unroll
        for (int n = 0; n < 8; ++n) xw_s[r][h * 8 + n] = x[n];
    }
    if (XF) {
        tb2[0][pstg0] = make_float2(p0.x, p0.y);    // step 0 -> buffer 0
        tb2[0][pstg1] = make_float2(p0.z, p0.w);
        p0 = psrc[1 * 256 + t256];                  // step 1 (in flight)
        p1 = psrc[2 * 256 + t256];                  // step 2 (in flight)
    }
    wg_barrier();

    // exclusive shift within segment + wave1 prepends wave0's total
    float xt[8];
#pragma unroll
    for (int n = 0; n < 8; ++n) xt[n] = xw_s[r][h * 8 + n];
#pragma unroll
    for (int n = 0; n < 8; ++n) {
        const float xi = __shfl_up(x[n], 1, 32);
        const float Pi = __shfl_up(P[n], 1, 32);
        const float xe = (c == 0) ? 0.f : xi;
        const float Pe = (c == 0) ? 1.f : Pi;
        x[n] = W ? fmaf(Pe, xt[n], xe) : xe;
    }

    // ---- Pass 2: rescan; 16 one-step epochs, depth-2 prefetch pipeline ----
    const float Dd = D_g[d];
    if (XF) {
#pragma unroll
        for (int i = 0; i < CL; ++i) {
            const float2 du = du_s[lb + i * ISTR2 + cg];
            const float dtp = du.x;
            const float uu = du.y;
            const float dtu = dtp * uu;
            const float2 b0 = tb2[i & 1][trb];
            const float2 b1 = tb2[i & 1][trb + 65];
            const float2 b2 = tb2[i & 1][trb + 130];
            const float2 b3 = tb2[i & 1][trb + 195];
            const float2 c0 = tb2[i & 1][TS2 + trb];
            const float2 c1 = tb2[i & 1][TS2 + trb + 65];
            const float2 c2 = tb2[i & 1][TS2 + trb + 130];
            const float2 c3 = tb2[i & 1][TS2 + trb + 195];
            const float bv[8] = {b0.x, b0.y, b1.x, b1.y, b2.x, b2.y, b3.x, b3.y};
            const float cv[8] = {c0.x, c0.y, c1.x, c1.y, c2.x, c2.y, c3.x, c3.y};
            float acc = 0.f;
#pragma unroll
            for (int n = 0; n < 8; ++n) {
                const float a = EXP2(dtp * A2[n]);
                x[n] = fmaf(a, x[n], dtu * bv[n]);
                acc = fmaf(x[n], cv[n], acc);
            }
            acc += __shfl_xor(acc, 32, 64);        // both halves get full sum
            const float yv = fmaf(uu, Dd, acc);
            y[i & 7] = ((i >> 3) == h) ? yv : y[i & 7];   // static idx
            if (i + 1 < CL) {                      // write step i+1 tile
                const float4 pv = (i & 1) ? p1 : p0;
                tb2[(i + 1) & 1][pstg0] = make_float2(pv.x, pv.y);
                tb2[(i + 1) & 1][pstg1] = make_float2(pv.z, pv.w);
            }
            if (i + 3 < CL) {                      // issue step i+3 (2 epochs ahead)
                if (i & 1) p1 = psrc[(i + 3) * 256 + t256];
                else       p0 = psrc[(i + 3) * 256 + t256];
            }
            if (i + 1 < CL) wg_barrier();
        }
    } else {
#pragma unroll
        for (int i = 0; i < CL; ++i) {
            const float2 du = du_s[lb + i * ISTR2 + cg];
            const float dtp = du.x;
            const float uu = du.y;
            const float dtu = dtp * uu;
            const int l = cg * CL + i;
            const int k0 = 2 * h;
            float4 B0, B1, C0, C1;
#pragma unroll
            for (int q = 0; q < 4; ++q) {
                (&B0.x)[q] = B_g[(size_t)(b * N + 4 * k0 + q) * L + l];
                (&B1.x)[q] = B_g[(size_t)(b * N + 4 * k0 + 4 + q) * L + l];
                (&C0.x)[q] = C_g[(size_t)(b * N + 4 * k0 + q) * L + l];
                (&C1.x)[q] = C_g[(size_t)(b * N + 4 * k0 + 4 + q) * L + l];
            }
            const float bv[8] = {B0.x, B0.y, B0.z, B0.w, B1.x, B1.y, B1.z, B1.w};
            const float cv[8] = {C0.x, C0.y, C0.z, C0.w, C1.x, C1.y, C1.z, C1.w};
            float acc = 0.f;
#pragma unroll
            for (int n = 0; n < 8; ++n) {
                const float a = EXP2(dtp * A2[n]);
                x[n] = fmaf(a, x[n], dtu * bv[n]);
                acc = fmaf(x[n], cv[n], acc);
            }
            acc += __shfl_xor(acc, 32, 64);
            const float yv = fmaf(uu, Dd, acc);
            y[i & 7] = ((i >> 3) == h) ? yv : y[i & 7];
        }
    }

    // ---- Epilogue: per-lane z read (32B), silu gate, y store from regs ----
    {
        const size_t gz = (size_t)row * L + cg * CL + h * 8;
        const float4 z0 = *reinterpret_cast<const float4*>(&z_g[gz]);
        const float4 z1 = *reinterpret_cast<const float4*>(&z_g[gz + 4]);
        float out[8];
#pragma unroll
        for (int j = 0; j < 8; ++j) {
            const float zv = (j < 4) ? (&z0.x)[j] : (&z1.x)[j - 4];
            const float e = EXP2(-zv * LOG2E);
            const float sig = __builtin_amdgcn_rcpf(1.f + e);
            out[j] = y[j] * (zv * sig);
        }
        *reinterpret_cast<float4*>(&y_g[gz]) =
            make_float4(out[0], out[1], out[2], out[3]);
        *reinterpret_cast<float4*>(&y_g[gz + 4]) =
            make_float4(out[4], out[5], out[6], out[7]);
    }
}

extern "C" void kernel_launch(void* const* d_in, const int* in_sizes, int n_in,
                              void* d_out, int out_size, void* d_ws, size_t ws_size,
                              hipStream_t stream) {
    const float* u     = (const float*)d_in[0];
    const float* delta = (const float*)d_in[1];
    const float* A     = (const float*)d_in[2];
    const float* B     = (const float*)d_in[3];
    const float* C     = (const float*)d_in[4];
    const float* D     = (const float*)d_in[5];
    const float* z     = (const float*)d_in[6];
    const float* bias  = (const float*)d_in[7];
    const int*   sp    = (const int*)d_in[8];
    float* y = (float*)d_out;

    const size_t bc_bytes = (size_t)Bsz * 4096 * sizeof(float4);  // 128 KB each
    const bool xf = ws_size >= 2 * bc_bytes;
    float4* Bs = (float4*)d_ws;
    float4* Cs = (float4*)((char*)d_ws + bc_bytes);

    if (xf) {
        transform_bc_kernel<<<dim3(16, Bsz, 2), 256, 0, stream>>>(B, C, Bs, Cs);
        mamba_scan19_kernel<true><<<dim3((Bsz * Dm) / RPB), TPB, 0, stream>>>(
            u, delta, A, B, C, Bs, Cs, D, z, bias, sp, y);
    } else {
        mamba_scan19_kernel<false><<<dim3((Bsz * Dm) / RPB), TPB, 0, stream>>>(
            u, delta, A, B, C, Bs, Cs, D, z, bias, sp, y);
    }
}

// Round 16
// 46.291 us; speedup vs baseline: 1.0716x; 1.0664x over previous
//
#include <hip/hip_runtime.h>
#include <math.h>

// Mamba selective scan:
//   u, delta, z : (2, 2048, 1024) f32 ; A : (2048, 16) f32
//   B, C : (2, 16, 1024) f32 ; D, delta_bias : (2048,) f32 ; softplus flag
// Output y : (2, 2048, 1024) f32
//
// v21 = v19 (49.4 us, PASSED: b64 tiles, non-draining barriers, depth-2
//       prefetch, y-in-regs) + packed-FP32 inner loops via NATIVE vector
//       types (r15 post-mortem: inline-asm v_pk_* got odd-aligned VGPR
//       pairs -> UB garbage; gfx90a+ requires even-aligned 64b tuples.
//       Native v2f32 ops use VReg_64_Align2 -> correct, and lower to
//       v_pk_mul_f32 / v_pk_fma_f32 when profitable).
//   - f32x2 math: tq = dd*A2p; e = exp2 per half; db = uu2*qv;
//     x2 = fma(e, x2, db); acc2 = fma(x2, qc, acc2).
//   - combine scalar (one unpack/repack per thread, once).
//   Tripwires: absmax == 0.0625, WRITE_SIZE == 16384 KB, VGPR <= 80.
constexpr int Bsz = 2, Dm = 2048, L = 1024, N = 16;
constexpr int CL = 16;          // chunk length (steps per lane)
constexpr int WPR = 2;          // waves per row
constexpr int RPB = 4;          // rows per block
constexpr int TPB = RPB * WPR * 64;  // 512
constexpr int NT = 8;           // pass-1 tiles (2 steps each)
constexpr int ISTR2 = 65;       // du_s float2 stride per step (64 + 1 pad)
constexpr int LROW2 = CL * ISTR2;    // 1040 float2 per row
constexpr int TS2 = 8 * 65;     // 520 float2: one step-group (8 j-rows x 65)
constexpr float LOG2E = 1.4426950408889634f;
constexpr float RLOG2E = 0.6931471805599453f;   // ln 2

#define EXP2(x) __builtin_amdgcn_exp2f(x)

typedef __attribute__((ext_vector_type(2))) float f32x2;

__device__ __forceinline__ f32x2 pk_fma(f32x2 a, f32x2 b, f32x2 c) {
    return __builtin_elementwise_fma(a, b, c);
}

// Workgroup barrier WITHOUT the vmcnt(0) drain __syncthreads inserts.
// lgkmcnt(0) makes this wave's LDS writes visible before the barrier;
// in-flight global->register loads keep counting across it.
__device__ __forceinline__ void wg_barrier() {
    asm volatile("s_waitcnt lgkmcnt(0)" ::: "memory");
    __builtin_amdgcn_s_barrier();
    asm volatile("" ::: "memory");
}

// ---------------------------------------------------------------------------
// Transform B,C into scan layout (chunk length 16), k-MAJOR:
//   Bs[b*4096 + i*256 + k*64 + cg] = float4 { B[b][4k+q][cg*16+i] } q=0..3
// Staging reads are then fully coalesced per tile.
// ---------------------------------------------------------------------------
__global__ __launch_bounds__(256) void transform_bc_kernel(
    const float* __restrict__ B_g, const float* __restrict__ C_g,
    float4* __restrict__ Bs, float4* __restrict__ Cs)
{
    const int o = threadIdx.x + 256 * blockIdx.x;   // 4096 float4 per (b, src)
    const int b = blockIdx.y;
    const float* __restrict__ src = blockIdx.z ? C_g : B_g;
    float4* __restrict__ dst = blockIdx.z ? Cs : Bs;
    const int cg = o & 63, k = (o >> 6) & 3, i = o >> 8;
    const int l = cg * CL + i;
    float4 v;
    v.x = src[(size_t)(b * N + 4 * k + 0) * L + l];
    v.y = src[(size_t)(b * N + 4 * k + 1) * L + l];
    v.z = src[(size_t)(b * N + 4 * k + 2) * L + l];
    v.w = src[(size_t)(b * N + 4 * k + 3) * L + l];
    dst[(size_t)b * 4096 + o] = v;
}

// ---------------------------------------------------------------------------
// Scan kernel. 8 waves/block = 4 rows x 2 waves. Wave handles 32 chunks of
// 16 steps. lane = h*32 + c: h = n-half, c = chunk-in-wave. cg = W*32+c.
// B/C tiles shared by all 4 rows via LDS (b64 conflict-free layout).
// ---------------------------------------------------------------------------
template<bool XF>
__global__ __launch_bounds__(TPB) void mamba_scan21_kernel(
    const float* __restrict__ u_g, const float* __restrict__ delta_g,
    const float* __restrict__ A_g,
    const float* __restrict__ B_g, const float* __restrict__ C_g,
    const float4* __restrict__ Bs, const float4* __restrict__ Cs,
    const float* __restrict__ D_g, const float* __restrict__ z_g,
    const float* __restrict__ bias_g, const int* __restrict__ sp_g,
    float* __restrict__ y_g)
{
    __shared__ float2 du_s[RPB * LROW2];  // [r][i*65+cg] = (dtp,u)
    __shared__ float2 tb2[2][2 * TS2];    // 16.6 KB tile ping-pong buffers
                                          // pass1: [buf][il*520 + j*65+cg]
                                          // pass2: [buf][bc*520 + j*65+cg]
    __shared__ float xw_s[RPB][16];       // per-row wave0 totals

    const int tid = threadIdx.x;
    const int wid = tid >> 6;                  // wave id 0..7
    const int lane = tid & 63;
    const int W = wid & 1;                     // wave-in-row
    const int r = wid >> 1;                    // local row 0..3
    const int h = lane >> 5;                   // n-half
    const int c = lane & 31;                   // chunk-in-wave
    const int cg = W * 32 + c;                 // global chunk 0..63
    const int row = blockIdx.x * RPB + r;
    const int b = row >> 11;                   // row / Dm (blocks never straddle)
    const int d = row & (Dm - 1);
    const size_t Bb = (size_t)b * 4096;        // workspace base (float4 units)
    const int lb = r * LROW2;
    const int t128 = tid & 127;                // thread-in-row (2 waves)
    // pass-1 staging: wave wid owns (il = wid>>2, k = wid&3) for all 64 cg
    const int stg0 = (wid >> 2) * TS2 + (2 * (wid & 3)) * 65 + lane;
    const int stg1 = stg0 + 65;
    // pass-2 staging: threads 0-255 stage B, 256-511 stage C (1 step each)
    const int bc = tid >> 8;
    const int t256 = tid & 255;
    const int pstg0 = bc * TS2 + (2 * ((t256 >> 6) & 3)) * 65 + (t256 & 63);
    const int pstg1 = pstg0 + 65;
    const float4* __restrict__ psrc = (bc ? Cs : Bs) + Bb;
    // tile read base for this lane: j = 4h at column cg
    const int trb = (4 * h) * 65 + cg;

    float4 s0, s1;
    if (XF) s0 = Bs[Bb + tid];                 // pass-1 tile 0, issued early

    // ---- Phase 0: coalesced load of delta/u -> step-major packed LDS ----
    {
        const float bias = bias_g[d];
        const int sp = sp_g[0];
#pragma unroll
        for (int p = 0; p < 2; ++p) {
            const int l0 = 4 * t128 + 512 * p;
            const size_t gb = (size_t)row * L + l0;
            const float4 d4 = *reinterpret_cast<const float4*>(&delta_g[gb]);
            const float4 u4 = *reinterpret_cast<const float4*>(&u_g[gb]);
#pragma unroll
            for (int k = 0; k < 4; ++k) {
                const int li = l0 + k;
                const float t = (&d4.x)[k] + bias;
                // softplus: max(t,0) + ln(1 + 2^(-|t|*log2e))
                const float e = EXP2(-fabsf(t) * LOG2E);
                const float p_ = sp ? (fmaxf(t, 0.f) +
                                       __builtin_amdgcn_logf(1.f + e) * RLOG2E)
                                    : t;
                const int a = (li & (CL - 1)) * ISTR2 + (li >> 4);
                du_s[lb + a] = make_float2(p_, (&u4.x)[k]);
            }
        }
    }
    float A2[8];
    f32x2 A2p[4];
#pragma unroll
    for (int g = 0; g < 2; ++g) {
        const float4 a4 = *reinterpret_cast<const float4*>(&A_g[d * N + h * 8 + g * 4]);
        A2[g * 4 + 0] = a4.x * LOG2E; A2[g * 4 + 1] = a4.y * LOG2E;
        A2[g * 4 + 2] = a4.z * LOG2E; A2[g * 4 + 3] = a4.w * LOG2E;
    }
#pragma unroll
    for (int q = 0; q < 4; ++q) { A2p[q].x = A2[2 * q]; A2p[q].y = A2[2 * q + 1]; }
    if (XF) {
        tb2[0][stg0] = make_float2(s0.x, s0.y);     // stage tile 0
        tb2[0][stg1] = make_float2(s0.z, s0.w);
        s0 = Bs[Bb + 512 + tid];                    // tile 1 (in flight)
        s1 = Bs[Bb + 1024 + tid];                   // tile 2 (in flight)
    }
    wg_barrier();

    // ---- Pass 1: zero-init scan; 8 epochs, depth-2 prefetch, pk math ----
    f32x2 x2[4];
#pragma unroll
    for (int q = 0; q < 4; ++q) { x2[q].x = 0.f; x2[q].y = 0.f; }
    float y[8];
#pragma unroll
    for (int n = 0; n < 8; ++n) y[n] = 0.f;
    float ssum = 0.f;

    if (XF) {
#pragma unroll
        for (int t = 0; t < NT; ++t) {
#pragma unroll
            for (int il = 0; il < 2; ++il) {
                const int i = 2 * t + il;
                const float2 du = du_s[lb + i * ISTR2 + cg];
                const float dtp = du.x;
                const float dtu = du.x * du.y;
                ssum += dtp;
                const int rb = il * TS2 + trb;
                f32x2 qv[4];
                qv[0] = *reinterpret_cast<const f32x2*>(&tb2[t & 1][rb]);
                qv[1] = *reinterpret_cast<const f32x2*>(&tb2[t & 1][rb + 65]);
                qv[2] = *reinterpret_cast<const f32x2*>(&tb2[t & 1][rb + 130]);
                qv[3] = *reinterpret_cast<const f32x2*>(&tb2[t & 1][rb + 195]);
                f32x2 dd; dd.x = dtp; dd.y = dtp;
                f32x2 uu2; uu2.x = dtu; uu2.y = dtu;
#pragma unroll
                for (int q = 0; q < 4; ++q) {
                    const f32x2 tq = dd * A2p[q];
                    f32x2 e; e.x = EXP2(tq.x); e.y = EXP2(tq.y);
                    const f32x2 db = uu2 * qv[q];
                    x2[q] = pk_fma(e, x2[q], db);
                }
            }
            if (t + 1 < NT) {                       // write tile t+1
                const float4 sv = (t & 1) ? s1 : s0;
                tb2[(t + 1) & 1][stg0] = make_float2(sv.x, sv.y);
                tb2[(t + 1) & 1][stg1] = make_float2(sv.z, sv.w);
            }
            if (t + 3 < NT) {                       // issue tile t+3
                if (t & 1) s1 = Bs[Bb + (t + 3) * 512 + tid];
                else       s0 = Bs[Bb + (t + 3) * 512 + tid];
            }
            if (t + 1 < NT) wg_barrier();
        }
    } else {
#pragma unroll
        for (int i = 0; i < CL; ++i) {
            const float2 du = du_s[lb + i * ISTR2 + cg];
            const float dtp = du.x;
            const float dtu = du.x * du.y;
            ssum += dtp;
            const int l = cg * CL + i;
            const int k0 = 2 * h;
            float4 B0, B1;
#pragma unroll
            for (int q = 0; q < 4; ++q) {
                (&B0.x)[q] = B_g[(size_t)(b * N + 4 * k0 + q) * L + l];
                (&B1.x)[q] = B_g[(size_t)(b * N + 4 * k0 + 4 + q) * L + l];
            }
            const float bv[8] = {B0.x, B0.y, B0.z, B0.w, B1.x, B1.y, B1.z, B1.w};
#pragma unroll
            for (int n = 0; n < 8; ++n) {
                const float a = EXP2(dtp * A2[n]);
                const float xs = (n & 1) ? x2[n >> 1].y : x2[n >> 1].x;
                const float xn = fmaf(a, xs, dtu * bv[n]);
                if (n & 1) x2[n >> 1].y = xn; else x2[n >> 1].x = xn;
            }
        }
    }

    // unpack to scalars for the combine
    float x[8];
#pragma unroll
    for (int q = 0; q < 4; ++q) { x[2 * q] = x2[q].x; x[2 * q + 1] = x2[q].y; }

    // issue pass-2 step 0 load (latency hides under the combine)
    float4 p0, p1;
    if (XF) p0 = psrc[t256];

    // ---- Combine level 1: 32-lane segmented inclusive scan of (P, x) ----
    float P[8];
#pragma unroll
    for (int n = 0; n < 8; ++n) P[n] = EXP2(A2[n] * ssum);
#pragma unroll
    for (int s = 1; s < 32; s <<= 1) {
        const bool ok = (c >= s);
#pragma unroll
        for (int n = 0; n < 8; ++n) {
            const float xp = __shfl_up(x[n], s, 32);
            const float Pp = __shfl_up(P[n], s, 32);
            if (ok) {
                x[n] = fmaf(P[n], xp, x[n]);
                P[n] = P[n] * Pp;
            }
        }
    }

    // ---- Combine level 2 publish + stage pass-2 step 0; ONE barrier ----
    if (W == 0 && c == 31) {
#pragma unroll
        for (int n = 0; n < 8; ++n) xw_s[r][h * 8 + n] = x[n];
    }
    if (XF) {
        tb2[0][pstg0] = make_float2(p0.x, p0.y);    // step 0 -> buffer 0
        tb2[0][pstg1] = make_float2(p0.z, p0.w);
        p0 = psrc[1 * 256 + t256];                  // step 1 (in flight)
        p1 = psrc[2 * 256 + t256];                  // step 2 (in flight)
    }
    wg_barrier();

    // exclusive shift within segment + wave1 prepends wave0's total
    float xt[8];
#pragma unroll
    for (int n = 0; n < 8; ++n) xt[n] = xw_s[r][h * 8 + n];
#pragma unroll
    for (int n = 0; n < 8; ++n) {
        const float xi = __shfl_up(x[n], 1, 32);
        const float Pi = __shfl_up(P[n], 1, 32);
        const float xe = (c == 0) ? 0.f : xi;
        const float Pe = (c == 0) ? 1.f : Pi;
        x[n] = W ? fmaf(Pe, xt[n], xe) : xe;
    }

    // repack for pass 2
#pragma unroll
    for (int q = 0; q < 4; ++q) { x2[q].x = x[2 * q]; x2[q].y = x[2 * q + 1]; }

    // ---- Pass 2: rescan; 16 one-step epochs, depth-2 prefetch, pk math ----
    const float Dd = D_g[d];
    if (XF) {
#pragma unroll
        for (int i = 0; i < CL; ++i) {
            const float2 du = du_s[lb + i * ISTR2 + cg];
            const float dtp = du.x;
            const float uu = du.y;
            const float dtu = dtp * uu;
            f32x2 qb[4], qc[4];
            qb[0] = *reinterpret_cast<const f32x2*>(&tb2[i & 1][trb]);
            qb[1] = *reinterpret_cast<const f32x2*>(&tb2[i & 1][trb + 65]);
            qb[2] = *reinterpret_cast<const f32x2*>(&tb2[i & 1][trb + 130]);
            qb[3] = *reinterpret_cast<const f32x2*>(&tb2[i & 1][trb + 195]);
            qc[0] = *reinterpret_cast<const f32x2*>(&tb2[i & 1][TS2 + trb]);
            qc[1] = *reinterpret_cast<const f32x2*>(&tb2[i & 1][TS2 + trb + 65]);
            qc[2] = *reinterpret_cast<const f32x2*>(&tb2[i & 1][TS2 + trb + 130]);
            qc[3] = *reinterpret_cast<const f32x2*>(&tb2[i & 1][TS2 + trb + 195]);
            f32x2 dd; dd.x = dtp; dd.y = dtp;
            f32x2 uu2; uu2.x = dtu; uu2.y = dtu;
            f32x2 acc2; acc2.x = 0.f; acc2.y = 0.f;
#pragma unroll
            for (int q = 0; q < 4; ++q) {
                const f32x2 tq = dd * A2p[q];
                f32x2 e; e.x = EXP2(tq.x); e.y = EXP2(tq.y);
                const f32x2 db = uu2 * qb[q];
                x2[q] = pk_fma(e, x2[q], db);
                acc2 = pk_fma(x2[q], qc[q], acc2);
            }
            float acc = acc2.x + acc2.y;
            acc += __shfl_xor(acc, 32, 64);        // both halves get full sum
            const float yv = fmaf(uu, Dd, acc);
            y[i & 7] = ((i >> 3) == h) ? yv : y[i & 7];   // static idx
            if (i + 1 < CL) {                      // write step i+1 tile
                const float4 pv = (i & 1) ? p1 : p0;
                tb2[(i + 1) & 1][pstg0] = make_float2(pv.x, pv.y);
                tb2[(i + 1) & 1][pstg1] = make_float2(pv.z, pv.w);
            }
            if (i + 3 < CL) {                      // issue step i+3
                if (i & 1) p1 = psrc[(i + 3) * 256 + t256];
                else       p0 = psrc[(i + 3) * 256 + t256];
            }
            if (i + 1 < CL) wg_barrier();
        }
    } else {
#pragma unroll
        for (int i = 0; i < CL; ++i) {
            const float2 du = du_s[lb + i * ISTR2 + cg];
            const float dtp = du.x;
            const float uu = du.y;
            const float dtu = dtp * uu;
            const int l = cg * CL + i;
            const int k0 = 2 * h;
            float4 B0, B1, C0, C1;
#pragma unroll
            for (int q = 0; q < 4; ++q) {
                (&B0.x)[q] = B_g[(size_t)(b * N + 4 * k0 + q) * L + l];
                (&B1.x)[q] = B_g[(size_t)(b * N + 4 * k0 + 4 + q) * L + l];
                (&C0.x)[q] = C_g[(size_t)(b * N + 4 * k0 + q) * L + l];
                (&C1.x)[q] = C_g[(size_t)(b * N + 4 * k0 + 4 + q) * L + l];
            }
            const float bv[8] = {B0.x, B0.y, B0.z, B0.w, B1.x, B1.y, B1.z, B1.w};
            const float cv[8] = {C0.x, C0.y, C0.z, C0.w, C1.x, C1.y, C1.z, C1.w};
            float acc = 0.f;
#pragma unroll
            for (int n = 0; n < 8; ++n) {
                const float a = EXP2(dtp * A2[n]);
                const float xs = (n & 1) ? x2[n >> 1].y : x2[n >> 1].x;
                const float xn = fmaf(a, xs, dtu * bv[n]);
                if (n & 1) x2[n >> 1].y = xn; else x2[n >> 1].x = xn;
                acc = fmaf(xn, cv[n], acc);
            }
            acc += __shfl_xor(acc, 32, 64);
            const float yv = fmaf(uu, Dd, acc);
            y[i & 7] = ((i >> 3) == h) ? yv : y[i & 7];
        }
    }

    // ---- Epilogue: per-lane z read (32B), silu gate, y store from regs ----
    {
        const size_t gz = (size_t)row * L + cg * CL + h * 8;
        const float4 z0 = *reinterpret_cast<const float4*>(&z_g[gz]);
        const float4 z1 = *reinterpret_cast<const float4*>(&z_g[gz + 4]);
        float out[8];
#pragma unroll
        for (int j = 0; j < 8; ++j) {
            const float zv = (j < 4) ? (&z0.x)[j] : (&z1.x)[j - 4];
            const float e = EXP2(-zv * LOG2E);
            const float sig = __builtin_amdgcn_rcpf(1.f + e);
            out[j] = y[j] * (zv * sig);
        }
        *reinterpret_cast<float4*>(&y_g[gz]) =
            make_float4(out[0], out[1], out[2], out[3]);
        *reinterpret_cast<float4*>(&y_g[gz + 4]) =
            make_float4(out[4], out[5], out[6], out[7]);
    }
}

extern "C" void kernel_launch(void* const* d_in, const int* in_sizes, int n_in,
                              void* d_out, int out_size, void* d_ws, size_t ws_size,
                              hipStream_t stream) {
    const float* u     = (const float*)d_in[0];
    const float* delta = (const float*)d_in[1];
    const float* A     = (const float*)d_in[2];
    const float* B     = (const float*)d_in[3];
    const float* C     = (const float*)d_in[4];
    const float* D     = (const float*)d_in[5];
    const float* z     = (const float*)d_in[6];
    const float* bias  = (const float*)d_in[7];
    const int*   sp    = (const int*)d_in[8];
    float* y = (float*)d_out;

    const size_t bc_bytes = (size_t)Bsz * 4096 * sizeof(float4);  // 128 KB each
    const bool xf = ws_size >= 2 * bc_bytes;
    float4* Bs = (float4*)d_ws;
    float4* Cs = (float4*)((char*)d_ws + bc_bytes);

    if (xf) {
        transform_bc_kernel<<<dim3(16, Bsz, 2), 256, 0, stream>>>(B, C, Bs, Cs);
        mamba_scan21_kernel<true><<<dim3((Bsz * Dm) / RPB), TPB, 0, stream>>>(
            u, delta, A, B, C, Bs, Cs, D, z, bias, sp, y);
    } else {
        mamba_scan21_kernel<false><<<dim3((Bsz * Dm) / RPB), TPB, 0, stream>>>(
            u, delta, A, B, C, Bs, Cs, D, z, bias, sp, y);
    }
}

// Round 18
// 43.206 us; speedup vs baseline: 1.1481x; 1.0714x over previous
//
#include <hip/hip_runtime.h>
#include <math.h>

// Mamba selective scan:
//   u, delta, z : (2, 2048, 1024) f32 ; A : (2048, 16) f32
//   B, C : (2, 16, 1024) f32 ; D, delta_bias : (2048,) f32 ; softplus flag
// Output y : (2, 2048, 1024) f32
//
// v23 = v22 with the UNVERIFIED v_permlane32_swap_b32 half-sum reverted to
//       v21's proven __shfl_xor(acc,32,64) (r17 post-mortem: permlane swap
//       operand semantics ambiguous -> partner select inverted -> absmax 131.
//       Rule: no unverified inline-asm lane ops.)
//   Keeps from v22 (r9-verified machinery only):
//   - scalar-ss DPP affine scan (row_shr:1/2/4/8 + row_bcast:15 w/ mask 0xA),
//     P[8] eliminated; exclusive shift via DPP with c==16 bcast select.
//   Keeps from v21: b64 conflict-free tiles, non-draining wg_barrier,
//   depth-2 prefetch, packed-f32 pass math, y-in-regs epilogue.
//   Tripwires: absmax <= 0.0625, WRITE_SIZE == 16384 KB, VGPR <= 72.
constexpr int Bsz = 2, Dm = 2048, L = 1024, N = 16;
constexpr int CL = 16;          // chunk length (steps per lane)
constexpr int WPR = 2;          // waves per row
constexpr int RPB = 4;          // rows per block
constexpr int TPB = RPB * WPR * 64;  // 512
constexpr int NT = 8;           // pass-1 tiles (2 steps each)
constexpr int ISTR2 = 65;       // du_s float2 stride per step (64 + 1 pad)
constexpr int LROW2 = CL * ISTR2;    // 1040 float2 per row
constexpr int TS2 = 8 * 65;     // 520 float2: one step-group (8 j-rows x 65)
constexpr float LOG2E = 1.4426950408889634f;
constexpr float RLOG2E = 0.6931471805599453f;   // ln 2

#define EXP2(x) __builtin_amdgcn_exp2f(x)

typedef __attribute__((ext_vector_type(2))) float f32x2;

__device__ __forceinline__ f32x2 pk_fma(f32x2 a, f32x2 b, f32x2 c) {
    return __builtin_elementwise_fma(a, b, c);
}

// DPP lane-shift on the VALU pipe; masked/invalid lanes receive old = 0
// (identity for the affine scan). ctrl: 0x111=row_shr:1 0x112=row_shr:2
// 0x114=row_shr:4 0x118=row_shr:8 0x142=row_bcast:15.
#define DPPF(CTRL, RM, v) __builtin_bit_cast(float, __builtin_amdgcn_update_dpp( \
        0, __builtin_bit_cast(int, (float)(v)), (CTRL), (RM), 0xF, false))

// One affine-scan stage over (ss, x[8]) with window-decay exp2(A2[n]*ss).
// r9-verified machinery (absmax-clean), incl. the 0xA mask on row_bcast.
#define COMBINE_STAGE(CTRL, RM) do {                                      \
    const float ssp_ = DPPF(CTRL, RM, ss);                                \
    float xp_[8];                                                         \
    _Pragma("unroll") for (int n_ = 0; n_ < 8; ++n_)                      \
        xp_[n_] = DPPF(CTRL, RM, x[n_]);                                  \
    _Pragma("unroll") for (int n_ = 0; n_ < 8; ++n_)                      \
        x[n_] = fmaf(EXP2(A2[n_] * ss), xp_[n_], x[n_]);                  \
    ss += ssp_;                                                           \
} while (0)

// Workgroup barrier WITHOUT the vmcnt(0) drain __syncthreads inserts.
// lgkmcnt(0) makes this wave's LDS writes visible before the barrier;
// in-flight global->register loads keep counting across it.
__device__ __forceinline__ void wg_barrier() {
    asm volatile("s_waitcnt lgkmcnt(0)" ::: "memory");
    __builtin_amdgcn_s_barrier();
    asm volatile("" ::: "memory");
}

// ---------------------------------------------------------------------------
// Transform B,C into scan layout (chunk length 16), k-MAJOR:
//   Bs[b*4096 + i*256 + k*64 + cg] = float4 { B[b][4k+q][cg*16+i] } q=0..3
// Staging reads are then fully coalesced per tile.
// ---------------------------------------------------------------------------
__global__ __launch_bounds__(256) void transform_bc_kernel(
    const float* __restrict__ B_g, const float* __restrict__ C_g,
    float4* __restrict__ Bs, float4* __restrict__ Cs)
{
    const int o = threadIdx.x + 256 * blockIdx.x;   // 4096 float4 per (b, src)
    const int b = blockIdx.y;
    const float* __restrict__ src = blockIdx.z ? C_g : B_g;
    float4* __restrict__ dst = blockIdx.z ? Cs : Bs;
    const int cg = o & 63, k = (o >> 6) & 3, i = o >> 8;
    const int l = cg * CL + i;
    float4 v;
    v.x = src[(size_t)(b * N + 4 * k + 0) * L + l];
    v.y = src[(size_t)(b * N + 4 * k + 1) * L + l];
    v.z = src[(size_t)(b * N + 4 * k + 2) * L + l];
    v.w = src[(size_t)(b * N + 4 * k + 3) * L + l];
    dst[(size_t)b * 4096 + o] = v;
}

// ---------------------------------------------------------------------------
// Scan kernel. 8 waves/block = 4 rows x 2 waves. Wave handles 32 chunks of
// 16 steps. lane = h*32 + c: h = n-half, c = chunk-in-wave. cg = W*32+c.
// B/C tiles shared by all 4 rows via LDS (b64 conflict-free layout).
// ---------------------------------------------------------------------------
template<bool XF>
__global__ __launch_bounds__(TPB) void mamba_scan23_kernel(
    const float* __restrict__ u_g, const float* __restrict__ delta_g,
    const float* __restrict__ A_g,
    const float* __restrict__ B_g, const float* __restrict__ C_g,
    const float4* __restrict__ Bs, const float4* __restrict__ Cs,
    const float* __restrict__ D_g, const float* __restrict__ z_g,
    const float* __restrict__ bias_g, const int* __restrict__ sp_g,
    float* __restrict__ y_g)
{
    __shared__ float2 du_s[RPB * LROW2];  // [r][i*65+cg] = (dtp,u)
    __shared__ float2 tb2[2][2 * TS2];    // 16.6 KB tile ping-pong buffers
    __shared__ float xw_s[RPB][16];       // per-row wave0 totals

    const int tid = threadIdx.x;
    const int wid = tid >> 6;                  // wave id 0..7
    const int lane = tid & 63;
    const int W = wid & 1;                     // wave-in-row
    const int r = wid >> 1;                    // local row 0..3
    const int h = lane >> 5;                   // n-half
    const int c = lane & 31;                   // chunk-in-wave
    const int cg = W * 32 + c;                 // global chunk 0..63
    const int row = blockIdx.x * RPB + r;
    const int b = row >> 11;                   // row / Dm (blocks never straddle)
    const int d = row & (Dm - 1);
    const size_t Bb = (size_t)b * 4096;        // workspace base (float4 units)
    const int lb = r * LROW2;
    const int t128 = tid & 127;                // thread-in-row (2 waves)
    // pass-1 staging: wave wid owns (il = wid>>2, k = wid&3) for all 64 cg
    const int stg0 = (wid >> 2) * TS2 + (2 * (wid & 3)) * 65 + lane;
    const int stg1 = stg0 + 65;
    // pass-2 staging: threads 0-255 stage B, 256-511 stage C (1 step each)
    const int bc = tid >> 8;
    const int t256 = tid & 255;
    const int pstg0 = bc * TS2 + (2 * ((t256 >> 6) & 3)) * 65 + (t256 & 63);
    const int pstg1 = pstg0 + 65;
    const float4* __restrict__ psrc = (bc ? Cs : Bs) + Bb;
    // tile read base for this lane: j = 4h at column cg
    const int trb = (4 * h) * 65 + cg;

    float4 s0, s1;
    if (XF) s0 = Bs[Bb + tid];                 // pass-1 tile 0, issued early

    // ---- Phase 0: coalesced load of delta/u -> step-major packed LDS ----
    {
        const float bias = bias_g[d];
        const int sp = sp_g[0];
#pragma unroll
        for (int p = 0; p < 2; ++p) {
            const int l0 = 4 * t128 + 512 * p;
            const size_t gb = (size_t)row * L + l0;
            const float4 d4 = *reinterpret_cast<const float4*>(&delta_g[gb]);
            const float4 u4 = *reinterpret_cast<const float4*>(&u_g[gb]);
#pragma unroll
            for (int k = 0; k < 4; ++k) {
                const int li = l0 + k;
                const float t = (&d4.x)[k] + bias;
                // softplus: max(t,0) + ln(1 + 2^(-|t|*log2e))
                const float e = EXP2(-fabsf(t) * LOG2E);
                const float p_ = sp ? (fmaxf(t, 0.f) +
                                       __builtin_amdgcn_logf(1.f + e) * RLOG2E)
                                    : t;
                const int a = (li & (CL - 1)) * ISTR2 + (li >> 4);
                du_s[lb + a] = make_float2(p_, (&u4.x)[k]);
            }
        }
    }
    float A2[8];
    f32x2 A2p[4];
#pragma unroll
    for (int g = 0; g < 2; ++g) {
        const float4 a4 = *reinterpret_cast<const float4*>(&A_g[d * N + h * 8 + g * 4]);
        A2[g * 4 + 0] = a4.x * LOG2E; A2[g * 4 + 1] = a4.y * LOG2E;
        A2[g * 4 + 2] = a4.z * LOG2E; A2[g * 4 + 3] = a4.w * LOG2E;
    }
#pragma unroll
    for (int q = 0; q < 4; ++q) { A2p[q].x = A2[2 * q]; A2p[q].y = A2[2 * q + 1]; }
    if (XF) {
        tb2[0][stg0] = make_float2(s0.x, s0.y);     // stage tile 0
        tb2[0][stg1] = make_float2(s0.z, s0.w);
        s0 = Bs[Bb + 512 + tid];                    // tile 1 (in flight)
        s1 = Bs[Bb + 1024 + tid];                   // tile 2 (in flight)
    }
    wg_barrier();

    // ---- Pass 1: zero-init scan; 8 epochs, depth-2 prefetch, pk math ----
    f32x2 x2[4];
#pragma unroll
    for (int q = 0; q < 4; ++q) { x2[q].x = 0.f; x2[q].y = 0.f; }
    float y[8];
#pragma unroll
    for (int n = 0; n < 8; ++n) y[n] = 0.f;
    float ss = 0.f;

    if (XF) {
#pragma unroll
        for (int t = 0; t < NT; ++t) {
#pragma unroll
            for (int il = 0; il < 2; ++il) {
                const int i = 2 * t + il;
                const float2 du = du_s[lb + i * ISTR2 + cg];
                const float dtp = du.x;
                const float dtu = du.x * du.y;
                ss += dtp;
                const int rb = il * TS2 + trb;
                f32x2 qv[4];
                qv[0] = *reinterpret_cast<const f32x2*>(&tb2[t & 1][rb]);
                qv[1] = *reinterpret_cast<const f32x2*>(&tb2[t & 1][rb + 65]);
                qv[2] = *reinterpret_cast<const f32x2*>(&tb2[t & 1][rb + 130]);
                qv[3] = *reinterpret_cast<const f32x2*>(&tb2[t & 1][rb + 195]);
                f32x2 dd; dd.x = dtp; dd.y = dtp;
                f32x2 uu2; uu2.x = dtu; uu2.y = dtu;
#pragma unroll
                for (int q = 0; q < 4; ++q) {
                    const f32x2 tq = dd * A2p[q];
                    f32x2 e; e.x = EXP2(tq.x); e.y = EXP2(tq.y);
                    const f32x2 db = uu2 * qv[q];
                    x2[q] = pk_fma(e, x2[q], db);
                }
            }
            if (t + 1 < NT) {                       // write tile t+1
                const float4 sv = (t & 1) ? s1 : s0;
                tb2[(t + 1) & 1][stg0] = make_float2(sv.x, sv.y);
                tb2[(t + 1) & 1][stg1] = make_float2(sv.z, sv.w);
            }
            if (t + 3 < NT) {                       // issue tile t+3
                if (t & 1) s1 = Bs[Bb + (t + 3) * 512 + tid];
                else       s0 = Bs[Bb + (t + 3) * 512 + tid];
            }
            if (t + 1 < NT) wg_barrier();
        }
    } else {
#pragma unroll
        for (int i = 0; i < CL; ++i) {
            const float2 du = du_s[lb + i * ISTR2 + cg];
            const float dtp = du.x;
            const float dtu = du.x * du.y;
            ss += dtp;
            const int l = cg * CL + i;
            const int k0 = 2 * h;
            float4 B0, B1;
#pragma unroll
            for (int q = 0; q < 4; ++q) {
                (&B0.x)[q] = B_g[(size_t)(b * N + 4 * k0 + q) * L + l];
                (&B1.x)[q] = B_g[(size_t)(b * N + 4 * k0 + 4 + q) * L + l];
            }
            const float bv[8] = {B0.x, B0.y, B0.z, B0.w, B1.x, B1.y, B1.z, B1.w};
#pragma unroll
            for (int n = 0; n < 8; ++n) {
                const float a = EXP2(dtp * A2[n]);
                const float xs = (n & 1) ? x2[n >> 1].y : x2[n >> 1].x;
                const float xn = fmaf(a, xs, dtu * bv[n]);
                if (n & 1) x2[n >> 1].y = xn; else x2[n >> 1].x = xn;
            }
        }
    }

    // unpack to scalars for the combine
    float x[8];
#pragma unroll
    for (int q = 0; q < 4; ++q) { x[2 * q] = x2[q].x; x[2 * q + 1] = x2[q].y; }

    // issue pass-2 step 0 load (latency hides under the combine)
    float4 p0, p1;
    if (XF) p0 = psrc[t256];

    // ---- Combine level 1: 32-lane segmented affine scan via DPP ----
    // After: x[n] = inclusive chunk-combine over [seg_start..c];
    //        ss   = inclusive dtp-prefix over the same window.
    COMBINE_STAGE(0x111, 0xF);   // row_shr:1
    COMBINE_STAGE(0x112, 0xF);   // row_shr:2
    COMBINE_STAGE(0x114, 0xF);   // row_shr:4
    COMBINE_STAGE(0x118, 0xF);   // row_shr:8
    COMBINE_STAGE(0x142, 0xA);   // row_bcast:15 -> rows 1,3 ONLY (r8 bug fix)

    // ---- Combine level 2 publish + stage pass-2 step 0; ONE barrier ----
    if (W == 0 && c == 31) {
#pragma unroll
        for (int n = 0; n < 8; ++n) xw_s[r][h * 8 + n] = x[n];
    }
    if (XF) {
        tb2[0][pstg0] = make_float2(p0.x, p0.y);    // step 0 -> buffer 0
        tb2[0][pstg1] = make_float2(p0.z, p0.w);
        p0 = psrc[1 * 256 + t256];                  // step 1 (in flight)
        p1 = psrc[2 * 256 + t256];                  // step 2 (in flight)
    }
    wg_barrier();

    // ---- Exclusive shift (DPP) + wave1 prepends wave0's totals ----
    {
        float xt[8];
#pragma unroll
        for (int n = 0; n < 8; ++n) xt[n] = xw_s[r][h * 8 + n];
        const float ss1 = DPPF(0x111, 0xF, ss);
        const float ssb = DPPF(0x142, 0xA, ss);
        const float sse = (c == 16) ? ssb : ss1;   // exclusive dtp-prefix
#pragma unroll
        for (int n = 0; n < 8; ++n) {
            const float x1 = DPPF(0x111, 0xF, x[n]);
            const float xb = DPPF(0x142, 0xA, x[n]);
            const float xe = (c == 16) ? xb : x1;  // exclusive within wave
            x[n] = W ? fmaf(EXP2(A2[n] * sse), xt[n], xe) : xe;
        }
    }

    // repack for pass 2
#pragma unroll
    for (int q = 0; q < 4; ++q) { x2[q].x = x[2 * q]; x2[q].y = x[2 * q + 1]; }

    // ---- Pass 2: rescan; 16 one-step epochs, depth-2 prefetch, pk math ----
    const float Dd = D_g[d];
    if (XF) {
#pragma unroll
        for (int i = 0; i < CL; ++i) {
            const float2 du = du_s[lb + i * ISTR2 + cg];
            const float dtp = du.x;
            const float uu = du.y;
            const float dtu = dtp * uu;
            f32x2 qb[4], qc[4];
            qb[0] = *reinterpret_cast<const f32x2*>(&tb2[i & 1][trb]);
            qb[1] = *reinterpret_cast<const f32x2*>(&tb2[i & 1][trb + 65]);
            qb[2] = *reinterpret_cast<const f32x2*>(&tb2[i & 1][trb + 130]);
            qb[3] = *reinterpret_cast<const f32x2*>(&tb2[i & 1][trb + 195]);
            qc[0] = *reinterpret_cast<const f32x2*>(&tb2[i & 1][TS2 + trb]);
            qc[1] = *reinterpret_cast<const f32x2*>(&tb2[i & 1][TS2 + trb + 65]);
            qc[2] = *reinterpret_cast<const f32x2*>(&tb2[i & 1][TS2 + trb + 130]);
            qc[3] = *reinterpret_cast<const f32x2*>(&tb2[i & 1][TS2 + trb + 195]);
            f32x2 dd; dd.x = dtp; dd.y = dtp;
            f32x2 uu2; uu2.x = dtu; uu2.y = dtu;
            f32x2 acc2; acc2.x = 0.f; acc2.y = 0.f;
#pragma unroll
            for (int q = 0; q < 4; ++q) {
                const f32x2 tq = dd * A2p[q];
                f32x2 e; e.x = EXP2(tq.x); e.y = EXP2(tq.y);
                const f32x2 db = uu2 * qb[q];
                x2[q] = pk_fma(e, x2[q], db);
                acc2 = pk_fma(x2[q], qc[q], acc2);
            }
            float acc = acc2.x + acc2.y;
            acc += __shfl_xor(acc, 32, 64);        // both halves get full sum
            const float yv = fmaf(uu, Dd, acc);
            y[i & 7] = ((i >> 3) == h) ? yv : y[i & 7];   // static idx
            if (i + 1 < CL) {                      // write step i+1 tile
                const float4 pv = (i & 1) ? p1 : p0;
                tb2[(i + 1) & 1][pstg0] = make_float2(pv.x, pv.y);
                tb2[(i + 1) & 1][pstg1] = make_float2(pv.z, pv.w);
            }
            if (i + 3 < CL) {                      // issue step i+3
                if (i & 1) p1 = psrc[(i + 3) * 256 + t256];
                else       p0 = psrc[(i + 3) * 256 + t256];
            }
            if (i + 1 < CL) wg_barrier();
        }
    } else {
#pragma unroll
        for (int i = 0; i < CL; ++i) {
            const float2 du = du_s[lb + i * ISTR2 + cg];
            const float dtp = du.x;
            const float uu = du.y;
            const float dtu = dtp * uu;
            const int l = cg * CL + i;
            const int k0 = 2 * h;
            float bv[8], cv[8];
#pragma unroll
            for (int q = 0; q < 8; ++q) {
                bv[q] = B_g[(size_t)(b * N + 4 * k0 + q) * L + l];
                cv[q] = C_g[(size_t)(b * N + 4 * k0 + q) * L + l];
            }
            float acc = 0.f;
#pragma unroll
            for (int n = 0; n < 8; ++n) {
                const float a = EXP2(dtp * A2[n]);
                const float xs = (n & 1) ? x2[n >> 1].y : x2[n >> 1].x;
                const float xn = fmaf(a, xs, dtu * bv[n]);
                if (n & 1) x2[n >> 1].y = xn; else x2[n >> 1].x = xn;
                acc = fmaf(xn, cv[n], acc);
            }
            acc += __shfl_xor(acc, 32, 64);
            const float yv = fmaf(uu, Dd, acc);
            y[i & 7] = ((i >> 3) == h) ? yv : y[i & 7];
        }
    }

    // ---- Epilogue: per-lane z read (32B), silu gate, y store from regs ----
    {
        const size_t gz = (size_t)row * L + cg * CL + h * 8;
        const float4 z0 = *reinterpret_cast<const float4*>(&z_g[gz]);
        const float4 z1 = *reinterpret_cast<const float4*>(&z_g[gz + 4]);
        float out[8];
#pragma unroll
        for (int j = 0; j < 8; ++j) {
            const float zv = (j < 4) ? (&z0.x)[j] : (&z1.x)[j - 4];
            const float e = EXP2(-zv * LOG2E);
            const float sig = __builtin_amdgcn_rcpf(1.f + e);
            out[j] = y[j] * (zv * sig);
        }
        *reinterpret_cast<float4*>(&y_g[gz]) =
            make_float4(out[0], out[1], out[2], out[3]);
        *reinterpret_cast<float4*>(&y_g[gz + 4]) =
            make_float4(out[4], out[5], out[6], out[7]);
    }
}

extern "C" void kernel_launch(void* const* d_in, const int* in_sizes, int n_in,
                              void* d_out, int out_size, void* d_ws, size_t ws_size,
                              hipStream_t stream) {
    const float* u     = (const float*)d_in[0];
    const float* delta = (const float*)d_in[1];
    const float* A     = (const float*)d_in[2];
    const float* B     = (const float*)d_in[3];
    const float* C     = (const float*)d_in[4];
    const float* D     = (const float*)d_in[5];
    const float* z     = (const float*)d_in[6];
    const float* bias  = (const float*)d_in[7];
    const int*   sp    = (const int*)d_in[8];
    float* y = (float*)d_out;

    const size_t bc_bytes = (size_t)Bsz * 4096 * sizeof(float4);  // 128 KB each
    const bool xf = ws_size >= 2 * bc_bytes;
    float4* Bs = (float4*)d_ws;
    float4* Cs = (float4*)((char*)d_ws + bc_bytes);

    if (xf) {
        transform_bc_kernel<<<dim3(16, Bsz, 2), 256, 0, stream>>>(B, C, Bs, Cs);
        mamba_scan23_kernel<true><<<dim3((Bsz * Dm) / RPB), TPB, 0, stream>>>(
            u, delta, A, B, C, Bs, Cs, D, z, bias, sp, y);
    } else {
        mamba_scan23_kernel<false><<<dim3((Bsz * Dm) / RPB), TPB, 0, stream>>>(
            u, delta, A, B, C, Bs, Cs, D, z, bias, sp, y);
    }
}